// Round 1
// baseline (111.491 us; speedup 1.0000x reference)
//
#include <hip/hip_runtime.h>
#include <math.h>

#define BB 4
#define NN 1024
#define DIN 128
#define DOUT 64
#define SLOPE 0.01f
#define RST 192  // x12y row stride (floats): [x1(64) | x2(64) | y(64)]

// ws layout: [0, 3 MB) = x12y (B*N*192 fp32)

// Kernel 1: wave-per-row projection. Also folds the OUTPUT linear layer:
// y = x @ lin_w^T per row, since (A@x)@lw^T == A@(x@lw^T) (associativity).
// This halves kernel-2's per-edge gather bytes and deletes its Phase E.
__global__ __launch_bounds__(64, 8) void proj_kernel(
    const float* __restrict__ x, const float* __restrict__ w1,
    const float* __restrict__ w2, const float* __restrict__ lin_w,
    float* __restrict__ x12y) {
  int l = threadIdx.x;
  int row = blockIdx.x;
  __shared__ __align__(16) float xl[DIN];
  reinterpret_cast<float2*>(xl)[l] =
      reinterpret_cast<const float2*>(x + (size_t)row * DIN)[l];
  __syncthreads();
  const float* w1c = w1 + l;
  const float* w2c = w2 + l;
  float a1 = 0.f, a2 = 0.f;
#pragma unroll 8
  for (int k = 0; k < DIN; ++k) {
    float xv = xl[k];                     // LDS broadcast
    a1 = fmaf(xv, w1c[k * DOUT], a1);     // coalesced 256B, L1-hot
    a2 = fmaf(xv, w2c[k * DOUT], a2);
  }
  // y_l = sum_k x_k * lin_w[l][k]; per-lane float4 stream of one 512B row.
  // lin_w is 32 KB total -> L1/L2-hot across the 4096 blocks.
  const float4* lw4 = reinterpret_cast<const float4*>(lin_w + (size_t)l * DIN);
  float a3 = 0.f;
#pragma unroll 8
  for (int k4 = 0; k4 < DIN / 4; ++k4) {
    float4 wv = lw4[k4];
    a3 = fmaf(xl[4 * k4 + 0], wv.x, a3);
    a3 = fmaf(xl[4 * k4 + 1], wv.y, a3);
    a3 = fmaf(xl[4 * k4 + 2], wv.z, a3);
    a3 = fmaf(xl[4 * k4 + 3], wv.w, a3);
  }
  size_t o = (size_t)row * RST;
  x12y[o + l] = a1;
  x12y[o + DOUT + l] = a2;
  x12y[o + 2 * DOUT + l] = a3;
}

__device__ __forceinline__ float fast_edge_exp(float sc) {
  // e = exp(8*tanh(sc/8)); tanh via exp, clamped so __expf stays finite
  float z = sc * 0.125f;
  z = fminf(10.f, fmaxf(-10.f, z));
  float u = __expf(2.f * z);
  float th = (u - 1.f) / (u + 1.f);
  return __expf(8.f * th);
}

// Kernel 2: TWO WAVES per (b,i) row (128 thr), grid 4096 -> 32 waves/CU.
// Wave w compacts mask columns [512w, 512w+512); edge list is two segments
// (seg0 at 0, seg1 at 512); phys(s) = s<nz0 ? s : 512+s-nz0.
__global__ __launch_bounds__(128, 8) void gat_row_kernel(
    const float* __restrict__ A_shape, const float* __restrict__ a_vec,
    const float* __restrict__ x12y, float* __restrict__ out) {
  int bi = blockIdx.x;  // b*N + i
  int b = bi >> 10;
  int tid = threadIdx.x;
  int lane = tid & 63;
  int w = tid >> 6;

  __shared__ int eidx[1040];                  // seg0:[0,512) seg1:[512,1040)
  __shared__ float evals[1040];
  __shared__ __align__(16) float x1s[DOUT];
  __shared__ __align__(16) float avs[DOUT];
  __shared__ float aggh[2][DOUT];
  __shared__ float wsum[2];
  __shared__ int cnt[2];

  if (tid < DOUT) {
    x1s[tid] = x12y[(size_t)bi * RST + tid];
    avs[tid] = a_vec[tid];
  }

  // ---- Phase A: each wave compacts its 512 mask columns ----
  const float* mask_row = A_shape + (size_t)bi * NN + w * 512;
  float mv[8];
#pragma unroll
  for (int c = 0; c < 8; ++c) mv[c] = mask_row[c * 64 + lane];
  int base = 0;
  int seg = w * 512;
#pragma unroll
  for (int c = 0; c < 8; ++c) {
    bool pred = (mv[c] != 0.f);
    unsigned long long m = __ballot(pred);
    int prefix = __popcll(m & ((1ull << lane) - 1ull));
    if (pred) eidx[seg + base + prefix] = w * 512 + c * 64 + lane;
    base += __popcll(m);  // wave-uniform
  }
  if (lane == 0) cnt[w] = base;
  __syncthreads();

  int nz0 = cnt[0], nz1 = cnt[1];
  int nzt = nz0 + nz1;
  int nzt16 = (nzt + 15) & ~15;
  if (tid < 16) {  // zero-weight pad edges after seg1 (capacity 512+16)
    eidx[512 + nz1 + tid] = bi & (NN - 1);
    evals[512 + nz1 + tid] = 0.f;
  }
  __syncthreads();

  // ---- Phase B: 8 groups x 16 lanes, 8 edges per iteration ----
  const float* x2b = x12y + (size_t)b * NN * RST + DOUT;  // x2, stride 192
  int l16 = tid & 15;
  int grp = tid >> 4;
  float4 x1v = reinterpret_cast<const float4*>(x1s)[l16];
  float4 avv = reinterpret_cast<const float4*>(avs)[l16];
  float lsum = 0.f;
  for (int s = grp; s < nzt; s += 8) {
    int ps = (s < nz0) ? s : 512 + s - nz0;
    int j = eidx[ps];
    float4 x2v = *reinterpret_cast<const float4*>(
        x2b + (size_t)j * RST + l16 * 4);  // 8 groups x 256B coalesced
    float z, sc = 0.f;
    z = x1v.x + x2v.x; sc = fmaf(z >= 0.f ? z : SLOPE * z, avv.x, sc);
    z = x1v.y + x2v.y; sc = fmaf(z >= 0.f ? z : SLOPE * z, avv.y, sc);
    z = x1v.z + x2v.z; sc = fmaf(z >= 0.f ? z : SLOPE * z, avv.z, sc);
    z = x1v.w + x2v.w; sc = fmaf(z >= 0.f ? z : SLOPE * z, avv.w, sc);
    sc += __shfl_xor(sc, 8, 16);
    sc += __shfl_xor(sc, 4, 16);
    sc += __shfl_xor(sc, 2, 16);
    sc += __shfl_xor(sc, 1, 16);
    if (l16 == 0) {
      float e = fast_edge_exp(sc);
      evals[ps] = e;
      lsum += e;
    }
  }

  // ---- Phase C: block-reduce row sum (leaders hold partials) ----
#pragma unroll
  for (int off = 32; off > 0; off >>= 1) lsum += __shfl_xor(lsum, off, 64);
  if (lane == 0) wsum[w] = lsum;
  __syncthreads();
  float inv = 1.f / (wsum[0] + wsum[1]);

  // ---- Phase D: aggregate y_j (64 floats/edge). Thread = (d, wave-half);
  // 16 edges per outer iter -> 8 independent 256B-coalesced loads/thread ----
  int d = tid & 63;
  int h = tid >> 6;
  const float* yb = x12y + (size_t)b * NN * RST + 2 * DOUT + d;
  float acc0 = 0.f, acc1 = 0.f;
  for (int s = 0; s < nzt16; s += 16) {
    int j[8];
    float wt[8];
#pragma unroll
    for (int r = 0; r < 8; ++r) {
      int ss = s + h + 2 * r;  // wave h covers edges s+h, s+h+2, ...
      int ps = (ss < nz0) ? ss : 512 + ss - nz0;
      j[r] = eidx[ps];   // wave-uniform LDS broadcast
      wt[r] = evals[ps];
    }
    float yv[8];
#pragma unroll
    for (int r = 0; r < 8; ++r) yv[r] = yb[(size_t)j[r] * RST];
#pragma unroll
    for (int r = 0; r < 8; r += 2) {
      acc0 = fmaf(wt[r], yv[r], acc0);
      acc1 = fmaf(wt[r + 1], yv[r + 1], acc1);
    }
  }
  aggh[h][d] = acc0 + acc1;
  __syncthreads();

  if (tid < DOUT) {
    float oo = (aggh[0][tid] + aggh[1][tid]) * inv;
    oo = oo >= 0.f ? oo : SLOPE * oo;
    out[(size_t)bi * DOUT + tid] = oo;
  }
}

extern "C" void kernel_launch(void* const* d_in, const int* in_sizes, int n_in,
                              void* d_out, int out_size, void* d_ws, size_t ws_size,
                              hipStream_t stream) {
  const float* x = (const float*)d_in[0];
  const float* A_shape = (const float*)d_in[1];
  const float* w1 = (const float*)d_in[2];
  const float* w2 = (const float*)d_in[3];
  const float* a = (const float*)d_in[4];
  const float* lin_w = (const float*)d_in[5];
  float* out = (float*)d_out;
  float* x12y = (float*)d_ws;  // B*N*192 fp32 = 3 MB

  proj_kernel<<<BB * NN, 64, 0, stream>>>(x, w1, w2, lin_w, x12y);
  gat_row_kernel<<<BB * NN, 128, 0, stream>>>(A_shape, a, x12y, out);
}

// Round 2
// 99.836 us; speedup vs baseline: 1.1167x; 1.1167x over previous
//
#include <hip/hip_runtime.h>
#include <math.h>

#define BB 4
#define NN 1024
#define DIN 128
#define DOUT 64
#define SLOPE 0.01f
#define RST 192  // x12y row stride (floats): [x1(64) | x2(64) | y(64)]
#define R1 16    // rows per block in proj_kernel

// ws layout: [0, 3 MB) = x12y (B*N*192 fp32)

// Kernel 1: 16-row-tiled projection GEMM. 256 blocks x 256 thr, 1 block/CU.
// Stages 16 x-rows + transposed lin_w in LDS; thread = (col d, rowgroup g),
// 4 rows x 3 outputs = 12 accumulators. Weight traffic cut 16x vs
// wave-per-row (4096 x 96 KB -> 256 x 96 KB); y = x @ lin_w^T folded here
// since (A@x)@lw^T == A@(x@lw^T).
__global__ __launch_bounds__(256, 2) void proj_kernel(
    const float* __restrict__ x, const float* __restrict__ w1,
    const float* __restrict__ w2, const float* __restrict__ lin_w,
    float* __restrict__ x12y) {
  int tid = threadIdx.x;
  int d = tid & 63;
  int g = tid >> 6;
  __shared__ __align__(16) float xl[R1][DIN];      // 8 KB
  __shared__ float lwT[DIN][DOUT + 1];             // 33.3 KB, pad kills bank conflicts
  int row0 = blockIdx.x * R1;

  {  // stage 16 x-rows: 2048 floats = 512 float4, coalesced
    const float4* xs = reinterpret_cast<const float4*>(x + (size_t)row0 * DIN);
    float4* xd = reinterpret_cast<float4*>(&xl[0][0]);
    xd[tid] = xs[tid];
    xd[tid + 256] = xs[tid + 256];
  }
#pragma unroll
  for (int i = 0; i < 32; ++i) {  // stage lin_w [64][128] -> lwT [128][65]
    int idx = i * 256 + tid;      // coalesced read; write banks (k+d)%32: conflict-free
    lwT[idx & 127][idx >> 7] = lin_w[idx];
  }
  __syncthreads();

  float a1[4] = {0.f, 0.f, 0.f, 0.f};
  float a2[4] = {0.f, 0.f, 0.f, 0.f};
  float a3[4] = {0.f, 0.f, 0.f, 0.f};
  const float* w1c = w1 + d;
  const float* w2c = w2 + d;
#pragma unroll 4
  for (int k = 0; k < DIN; ++k) {
    float wv1 = w1c[k * DOUT];   // 256B/wave, L1-hot
    float wv2 = w2c[k * DOUT];
    float wv3 = lwT[k][d];       // LDS, conflict-free
#pragma unroll
    for (int r = 0; r < 4; ++r) {
      float xv = xl[g * 4 + r][k];  // LDS broadcast
      a1[r] = fmaf(xv, wv1, a1[r]);
      a2[r] = fmaf(xv, wv2, a2[r]);
      a3[r] = fmaf(xv, wv3, a3[r]);
    }
  }
#pragma unroll
  for (int r = 0; r < 4; ++r) {
    size_t o = (size_t)(row0 + g * 4 + r) * RST;
    x12y[o + d] = a1[r];              // 256B coalesced per wave
    x12y[o + DOUT + d] = a2[r];
    x12y[o + 2 * DOUT + d] = a3[r];
  }
}

__device__ __forceinline__ float fast_edge_exp(float sc) {
  // e = exp(8*tanh(sc/8)); tanh via exp, clamped so __expf stays finite
  float z = sc * 0.125f;
  z = fminf(10.f, fmaxf(-10.f, z));
  float u = __expf(2.f * z);
  float th = (u - 1.f) / (u + 1.f);
  return __expf(8.f * th);
}

// Kernel 2: TWO WAVES per (b,i) row (128 thr), grid 4096 -> 32 waves/CU.
// Wave w compacts mask columns [512w, 512w+512); edge list is two segments
// (seg0 at 0, seg1 at 512); phys(s) = s<nz0 ? s : 512+s-nz0.
__global__ __launch_bounds__(128, 8) void gat_row_kernel(
    const float* __restrict__ A_shape, const float* __restrict__ a_vec,
    const float* __restrict__ x12y, float* __restrict__ out) {
  int bi = blockIdx.x;  // b*N + i
  int b = bi >> 10;
  int tid = threadIdx.x;
  int lane = tid & 63;
  int w = tid >> 6;

  __shared__ int eidx[1040];                  // seg0:[0,512) seg1:[512,1040)
  __shared__ float evals[1040];
  __shared__ __align__(16) float x1s[DOUT];
  __shared__ __align__(16) float avs[DOUT];
  __shared__ float aggh[2][DOUT];
  __shared__ float wsum[2];
  __shared__ int cnt[2];

  if (tid < DOUT) {
    x1s[tid] = x12y[(size_t)bi * RST + tid];
    avs[tid] = a_vec[tid];
  }

  // ---- Phase A: each wave compacts its 512 mask columns ----
  const float* mask_row = A_shape + (size_t)bi * NN + w * 512;
  float mv[8];
#pragma unroll
  for (int c = 0; c < 8; ++c) mv[c] = mask_row[c * 64 + lane];
  int base = 0;
  int seg = w * 512;
#pragma unroll
  for (int c = 0; c < 8; ++c) {
    bool pred = (mv[c] != 0.f);
    unsigned long long m = __ballot(pred);
    int prefix = __popcll(m & ((1ull << lane) - 1ull));
    if (pred) eidx[seg + base + prefix] = w * 512 + c * 64 + lane;
    base += __popcll(m);  // wave-uniform
  }
  if (lane == 0) cnt[w] = base;
  __syncthreads();

  int nz0 = cnt[0], nz1 = cnt[1];
  int nzt = nz0 + nz1;
  int nzt16 = (nzt + 15) & ~15;
  if (tid < 16) {  // zero-weight pad edges after seg1 (capacity 512+16)
    eidx[512 + nz1 + tid] = bi & (NN - 1);
    evals[512 + nz1 + tid] = 0.f;
  }
  __syncthreads();

  // ---- Phase B: 8 groups x 16 lanes, 8 edges per iteration ----
  const float* x2b = x12y + (size_t)b * NN * RST + DOUT;  // x2, stride 192
  int l16 = tid & 15;
  int grp = tid >> 4;
  float4 x1v = reinterpret_cast<const float4*>(x1s)[l16];
  float4 avv = reinterpret_cast<const float4*>(avs)[l16];
  float lsum = 0.f;
  for (int s = grp; s < nzt; s += 8) {
    int ps = (s < nz0) ? s : 512 + s - nz0;
    int j = eidx[ps];
    float4 x2v = *reinterpret_cast<const float4*>(
        x2b + (size_t)j * RST + l16 * 4);  // 8 groups x 256B coalesced
    float z, sc = 0.f;
    z = x1v.x + x2v.x; sc = fmaf(z >= 0.f ? z : SLOPE * z, avv.x, sc);
    z = x1v.y + x2v.y; sc = fmaf(z >= 0.f ? z : SLOPE * z, avv.y, sc);
    z = x1v.z + x2v.z; sc = fmaf(z >= 0.f ? z : SLOPE * z, avv.z, sc);
    z = x1v.w + x2v.w; sc = fmaf(z >= 0.f ? z : SLOPE * z, avv.w, sc);
    sc += __shfl_xor(sc, 8, 16);
    sc += __shfl_xor(sc, 4, 16);
    sc += __shfl_xor(sc, 2, 16);
    sc += __shfl_xor(sc, 1, 16);
    if (l16 == 0) {
      float e = fast_edge_exp(sc);
      evals[ps] = e;
      lsum += e;
    }
  }

  // ---- Phase C: block-reduce row sum (leaders hold partials) ----
#pragma unroll
  for (int off = 32; off > 0; off >>= 1) lsum += __shfl_xor(lsum, off, 64);
  if (lane == 0) wsum[w] = lsum;
  __syncthreads();
  float inv = 1.f / (wsum[0] + wsum[1]);

  // ---- Phase D: aggregate y_j (64 floats/edge). Thread = (d, wave-half);
  // 16 edges per outer iter -> 8 independent 256B-coalesced loads/thread ----
  int d = tid & 63;
  int h = tid >> 6;
  const float* yb = x12y + (size_t)b * NN * RST + 2 * DOUT + d;
  float acc0 = 0.f, acc1 = 0.f;
  for (int s = 0; s < nzt16; s += 16) {
    int j[8];
    float wt[8];
#pragma unroll
    for (int r = 0; r < 8; ++r) {
      int ss = s + h + 2 * r;  // wave h covers edges s+h, s+h+2, ...
      int ps = (ss < nz0) ? ss : 512 + ss - nz0;
      j[r] = eidx[ps];   // wave-uniform LDS broadcast
      wt[r] = evals[ps];
    }
    float yv[8];
#pragma unroll
    for (int r = 0; r < 8; ++r) yv[r] = yb[(size_t)j[r] * RST];
#pragma unroll
    for (int r = 0; r < 8; r += 2) {
      acc0 = fmaf(wt[r], yv[r], acc0);
      acc1 = fmaf(wt[r + 1], yv[r + 1], acc1);
    }
  }
  aggh[h][d] = acc0 + acc1;
  __syncthreads();

  if (tid < DOUT) {
    float oo = (aggh[0][tid] + aggh[1][tid]) * inv;
    oo = oo >= 0.f ? oo : SLOPE * oo;
    out[(size_t)bi * DOUT + tid] = oo;
  }
}

extern "C" void kernel_launch(void* const* d_in, const int* in_sizes, int n_in,
                              void* d_out, int out_size, void* d_ws, size_t ws_size,
                              hipStream_t stream) {
  const float* x = (const float*)d_in[0];
  const float* A_shape = (const float*)d_in[1];
  const float* w1 = (const float*)d_in[2];
  const float* w2 = (const float*)d_in[3];
  const float* a = (const float*)d_in[4];
  const float* lin_w = (const float*)d_in[5];
  float* out = (float*)d_out;
  float* x12y = (float*)d_ws;  // B*N*192 fp32 = 3 MB

  proj_kernel<<<BB * NN / R1, 256, 0, stream>>>(x, w1, w2, lin_w, x12y);
  gat_row_kernel<<<BB * NN, 128, 0, stream>>>(A_shape, a, x12y, out);
}

// Round 3
// 99.180 us; speedup vs baseline: 1.1241x; 1.0066x over previous
//
#include <hip/hip_runtime.h>
#include <math.h>

#define BB 4
#define NN 1024
#define DIN 128
#define DOUT 64
#define SLOPE 0.01f
#define RST 192  // x12y row stride (floats): [x1(64) | x2(64) | y(64)]
#define R1 8     // rows per block in proj_kernel (8 -> 512 blocks, 2/CU)

// ws layout: [0, 3 MB) = x12y (B*N*192 fp32)

// Kernel 1: 8-row-tiled projection GEMM. 512 blocks x 256 thr, 2 blocks/CU
// (8 waves/CU for latency hiding; w1/w2 streams shared L1-hot between the
// co-resident blocks). y = x @ lin_w^T folded here: (A@x)@lw^T == A@(x@lw^T).
__global__ __launch_bounds__(256, 2) void proj_kernel(
    const float* __restrict__ x, const float* __restrict__ w1,
    const float* __restrict__ w2, const float* __restrict__ lin_w,
    float* __restrict__ x12y) {
  int tid = threadIdx.x;
  int d = tid & 63;
  int g = tid >> 6;
  __shared__ __align__(16) float xl[R1][DIN];      // 4 KB
  __shared__ float lwT[DIN][DOUT + 1];             // 33.3 KB, pad kills bank conflicts
  int row0 = blockIdx.x * R1;

  {  // stage 8 x-rows: 1024 floats = 256 float4, coalesced
    const float4* xs = reinterpret_cast<const float4*>(x + (size_t)row0 * DIN);
    reinterpret_cast<float4*>(&xl[0][0])[tid] = xs[tid];
  }
#pragma unroll
  for (int i = 0; i < 32; ++i) {  // stage lin_w [64][128] -> lwT [128][65]
    int idx = i * 256 + tid;      // coalesced read; write stride 65: conflict-free
    lwT[idx & 127][idx >> 7] = lin_w[idx];
  }
  __syncthreads();

  float a1[2] = {0.f, 0.f};
  float a2[2] = {0.f, 0.f};
  float a3[2] = {0.f, 0.f};
  const float* w1c = w1 + d;
  const float* w2c = w2 + d;
#pragma unroll 4
  for (int k = 0; k < DIN; ++k) {
    float wv1 = w1c[k * DOUT];   // 256B/wave, L1-hot
    float wv2 = w2c[k * DOUT];
    float wv3 = lwT[k][d];       // LDS, conflict-free
#pragma unroll
    for (int r = 0; r < 2; ++r) {
      float xv = xl[g * 2 + r][k];  // LDS broadcast
      a1[r] = fmaf(xv, wv1, a1[r]);
      a2[r] = fmaf(xv, wv2, a2[r]);
      a3[r] = fmaf(xv, wv3, a3[r]);
    }
  }
#pragma unroll
  for (int r = 0; r < 2; ++r) {
    size_t o = (size_t)(row0 + g * 2 + r) * RST;
    x12y[o + d] = a1[r];              // 256B coalesced per wave
    x12y[o + DOUT + d] = a2[r];
    x12y[o + 2 * DOUT + d] = a3[r];
  }
}

__device__ __forceinline__ float fast_edge_exp(float sc) {
  // e = exp(8*tanh(sc/8)); tanh via exp, clamped so __expf stays finite
  float z = sc * 0.125f;
  z = fminf(10.f, fmaxf(-10.f, z));
  float u = __expf(2.f * z);
  float th = (u - 1.f) / (u + 1.f);
  return __expf(8.f * th);
}

// Kernel 2: TWO WAVES per (b,i) row (128 thr), grid 4096 -> 32 waves/CU.
// Wave w compacts mask columns [512w, 512w+512); edge list is two segments
// (seg0 at 0, seg1 at 512); phys(s) = s<nz0 ? s : 512+s-nz0.
// SINGLE edge pass: score + exp + y-aggregation fused (normalization
// deferred: out = agg * 16/sum, 16x because all 16 lanes of a score group
// accumulate their group's e into lsum).
__global__ __launch_bounds__(128, 8) void gat_row_kernel(
    const float* __restrict__ A_shape, const float* __restrict__ a_vec,
    const float* __restrict__ x12y, float* __restrict__ out) {
  int bi = blockIdx.x;  // b*N + i
  int b = bi >> 10;
  int tid = threadIdx.x;
  int lane = tid & 63;
  int w = tid >> 6;

  __shared__ int eidx[1040];                  // seg0:[0,512) seg1:[512,1040)
  __shared__ __align__(16) float x1s[DOUT];
  __shared__ __align__(16) float avs[DOUT];
  __shared__ float aggh[2][DOUT];
  __shared__ float wsum[2];
  __shared__ int cnt[2];

  if (tid < DOUT) {
    x1s[tid] = x12y[(size_t)bi * RST + tid];
    avs[tid] = a_vec[tid];
  }

  // ---- Phase A: each wave compacts its 512 mask columns ----
  const float* mask_row = A_shape + (size_t)bi * NN + w * 512;
  float mv[8];
#pragma unroll
  for (int c = 0; c < 8; ++c) mv[c] = mask_row[c * 64 + lane];
  int base = 0;
  int seg = w * 512;
#pragma unroll
  for (int c = 0; c < 8; ++c) {
    bool pred = (mv[c] != 0.f);
    unsigned long long m = __ballot(pred);
    int prefix = __popcll(m & ((1ull << lane) - 1ull));
    if (pred) eidx[seg + base + prefix] = w * 512 + c * 64 + lane;
    base += __popcll(m);  // wave-uniform
  }
  if (lane == 0) cnt[w] = base;
  __syncthreads();

  int nz0 = cnt[0], nz1 = cnt[1];
  int nzt = nz0 + nz1;
  int nzt8 = (nzt + 7) & ~7;
  if (tid < 8) {  // pad edges after seg1 point at a valid row; e forced to 0
    eidx[512 + nz1 + tid] = bi & (NN - 1);
  }
  __syncthreads();

  // ---- Fused edge pass: 8 edges/iter (4 per wave, one per 16-lane group).
  // Group computes its edge's score; all lanes take exp (branch-free, same
  // issue cost); 4 wave-shuffles broadcast e; y gathered by all 64 lanes
  // in parallel with the score chain. ----
  const float* x2b = x12y + (size_t)b * NN * RST + DOUT;        // x2, stride 192
  const float* yb = x12y + (size_t)b * NN * RST + 2 * DOUT + lane;  // y col
  int l16 = tid & 15;
  int g0 = lane >> 4;  // this lane's score group
  float4 x1v = reinterpret_cast<const float4*>(x1s)[l16];
  float4 avv = reinterpret_cast<const float4*>(avs)[l16];
  float lsum = 0.f;
  float acc = 0.f;
  for (int s0 = 0; s0 < nzt8; s0 += 8) {
    int jj[4];
#pragma unroll
    for (int g2 = 0; g2 < 4; ++g2) {
      int ss = s0 + 4 * w + g2;
      int ps = (ss < nz0) ? ss : 512 + ss - nz0;
      jj[g2] = eidx[ps];  // wave-uniform LDS broadcast
    }
    // y gathers: 4 x 256B coalesced, independent of the score chain
    float yv[4];
#pragma unroll
    for (int g2 = 0; g2 < 4; ++g2) yv[g2] = yb[(size_t)jj[g2] * RST];
    // score for own group's edge
    float4 x2v = *reinterpret_cast<const float4*>(
        x2b + (size_t)jj[g0] * RST + l16 * 4);  // 4 groups x 64B coalesced
    float z, sc = 0.f;
    z = x1v.x + x2v.x; sc = fmaf(z >= 0.f ? z : SLOPE * z, avv.x, sc);
    z = x1v.y + x2v.y; sc = fmaf(z >= 0.f ? z : SLOPE * z, avv.y, sc);
    z = x1v.z + x2v.z; sc = fmaf(z >= 0.f ? z : SLOPE * z, avv.z, sc);
    z = x1v.w + x2v.w; sc = fmaf(z >= 0.f ? z : SLOPE * z, avv.w, sc);
    sc += __shfl_xor(sc, 8, 16);
    sc += __shfl_xor(sc, 4, 16);
    sc += __shfl_xor(sc, 2, 16);
    sc += __shfl_xor(sc, 1, 16);
    float e = fast_edge_exp(sc);
    if (s0 + 4 * w + g0 >= nzt) e = 0.f;  // mask pad edges
    lsum += e;
#pragma unroll
    for (int g2 = 0; g2 < 4; ++g2) {
      float eg = __shfl(e, g2 * 16, 64);
      acc = fmaf(eg, yv[g2], acc);
    }
  }

  // ---- reduce row sum (lsum carries a 16x factor) + combine ----
#pragma unroll
  for (int off = 32; off > 0; off >>= 1) lsum += __shfl_xor(lsum, off, 64);
  if (lane == 0) wsum[w] = lsum;
  aggh[w][lane] = acc;
  __syncthreads();

  if (tid < DOUT) {
    float inv = 16.f / (wsum[0] + wsum[1]);
    float oo = (aggh[0][tid] + aggh[1][tid]) * inv;
    oo = oo >= 0.f ? oo : SLOPE * oo;
    out[(size_t)bi * DOUT + tid] = oo;
  }
}

extern "C" void kernel_launch(void* const* d_in, const int* in_sizes, int n_in,
                              void* d_out, int out_size, void* d_ws, size_t ws_size,
                              hipStream_t stream) {
  const float* x = (const float*)d_in[0];
  const float* A_shape = (const float*)d_in[1];
  const float* w1 = (const float*)d_in[2];
  const float* w2 = (const float*)d_in[3];
  const float* a = (const float*)d_in[4];
  const float* lin_w = (const float*)d_in[5];
  float* out = (float*)d_out;
  float* x12y = (float*)d_ws;  // B*N*192 fp32 = 3 MB

  proj_kernel<<<BB * NN / R1, 256, 0, stream>>>(x, w1, w2, lin_w, x12y);
  gat_row_kernel<<<BB * NN, 128, 0, stream>>>(A_shape, a, x12y, out);
}

// Round 4
// 97.976 us; speedup vs baseline: 1.1379x; 1.0123x over previous
//
#include <hip/hip_runtime.h>
#include <math.h>

#define BB 4
#define NN 1024
#define DIN 128
#define DOUT 64
#define SLOPE 0.01f
#define RST 192      // x12y row stride (floats): [x1(64) | x2(64) | y(64)]
#define R1 8         // rows per projection block
#define NPROJ (BB * NN / R1)   // 512 projection blocks
#define NCOMP (BB * NN / 4)    // 1024 compaction blocks (4 rows each)
#define ESTRIDE 1056 // u16 elems per edge-list row (8B aligned; max used 1028)

// ws layout:
//   [0)        x12y : BB*NN*RST f32  = 3 MB
//   [3145728)  cnt  : BB*NN i32      = 16 KB
//   [3162112)  ews  : BB*NN*ESTRIDE u16 = 8.6 MB

__device__ __forceinline__ float fast_edge_exp(float sc) {
  // e = exp(8*tanh(sc/8)); tanh via exp, clamped so __expf stays finite
  float z = sc * 0.125f;
  z = fminf(10.f, fmaxf(-10.f, z));
  float u = __expf(2.f * z);
  float th = (u - 1.f) / (u + 1.f);
  return __expf(8.f * th);
}

// Kernel 1: heterogeneous grid.
//  blocks [0,512): 8-row projection GEMM tile (y = x@lw^T folded in, since
//    (A@x)@lw^T == A@(x@lw^T)).
//  blocks [512,1536): mask compaction, one wave per row -> u16 edge lists.
//  Compaction is independent of projection, so the 16 MB mask HBM read
//  overlaps the projection compute instead of serializing in kernel 2.
__global__ __launch_bounds__(256, 2) void proj_compact_kernel(
    const float* __restrict__ x, const float* __restrict__ w1,
    const float* __restrict__ w2, const float* __restrict__ lin_w,
    const float* __restrict__ A_shape, float* __restrict__ x12y,
    int* __restrict__ cnt, unsigned short* __restrict__ ews) {
  int tid = threadIdx.x;

  if (blockIdx.x >= NPROJ) {
    // ---- compaction path: 4 rows/block, one per wave, wave-synchronous ----
    int lane = tid & 63;
    int r = (blockIdx.x - NPROJ) * 4 + (tid >> 6);   // global row bi
    const float* mask_row = A_shape + (size_t)r * NN;
    float mv[16];
#pragma unroll
    for (int c = 0; c < 16; ++c) mv[c] = mask_row[c * 64 + lane];
    unsigned short* er = ews + (size_t)r * ESTRIDE;
    int base = 0;
#pragma unroll
    for (int c = 0; c < 16; ++c) {
      bool pred = (mv[c] != 0.f);
      unsigned long long m = __ballot(pred);
      int prefix = __popcll(m & ((1ull << lane) - 1ull));
      if (pred) er[base + prefix] = (unsigned short)(c * 64 + lane);
      base += __popcll(m);  // wave-uniform
    }
    if (lane < 4) er[base + lane] = (unsigned short)(r & (NN - 1));  // pads
    if (lane == 0) cnt[r] = base;
    return;
  }

  // ---- projection path ----
  int d = tid & 63;
  int g = tid >> 6;
  __shared__ __align__(16) float xl[R1][DIN];      // 4 KB
  __shared__ float lwT[DIN][DOUT + 1];             // 33.3 KB, pad: no bank conflicts
  int row0 = blockIdx.x * R1;

  {  // stage 8 x-rows: 1024 floats = 256 float4, coalesced
    const float4* xs = reinterpret_cast<const float4*>(x + (size_t)row0 * DIN);
    reinterpret_cast<float4*>(&xl[0][0])[tid] = xs[tid];
  }
#pragma unroll
  for (int i = 0; i < 32; ++i) {  // stage lin_w [64][128] -> lwT [128][65]
    int idx = i * 256 + tid;      // coalesced read; write stride 65: conflict-free
    lwT[idx & 127][idx >> 7] = lin_w[idx];
  }
  __syncthreads();

  float a1[2] = {0.f, 0.f};
  float a2[2] = {0.f, 0.f};
  float a3[2] = {0.f, 0.f};
  const float* w1c = w1 + d;
  const float* w2c = w2 + d;
#pragma unroll 4
  for (int k = 0; k < DIN; ++k) {
    float wv1 = w1c[k * DOUT];   // 256B/wave, L1-hot
    float wv2 = w2c[k * DOUT];
    float wv3 = lwT[k][d];       // LDS, conflict-free
#pragma unroll
    for (int r = 0; r < 2; ++r) {
      float xv = xl[g * 2 + r][k];  // LDS broadcast
      a1[r] = fmaf(xv, wv1, a1[r]);
      a2[r] = fmaf(xv, wv2, a2[r]);
      a3[r] = fmaf(xv, wv3, a3[r]);
    }
  }
#pragma unroll
  for (int r = 0; r < 2; ++r) {
    size_t o = (size_t)(row0 + g * 2 + r) * RST;
    x12y[o + d] = a1[r];              // 256B coalesced per wave
    x12y[o + DOUT + d] = a2[r];
    x12y[o + 2 * DOUT + d] = a3[r];
  }
}

// Kernel 2: pure edge pass. ONE WAVE per (b,i) row, zero LDS, zero barriers.
// 4 edges/iter (one per 16-lane group) loaded as a single u64 of u16 idxs;
// score + exp + y-aggregation fused; normalization deferred (out = acc*16/sum
// since all 16 lanes of a group accumulate their e into lsum).
__global__ __launch_bounds__(64, 8) void gat_edge_kernel(
    const float* __restrict__ a_vec, const float* __restrict__ x12y,
    const int* __restrict__ cnt, const unsigned short* __restrict__ ews,
    float* __restrict__ out) {
  int bi = blockIdx.x;  // b*N + i
  int b = bi >> 10;
  int lane = threadIdx.x;
  int l16 = lane & 15;
  int g0 = lane >> 4;

  int nzt = cnt[bi];
  int nzt4 = (nzt + 3) & ~3;
  float4 x1v = reinterpret_cast<const float4*>(x12y + (size_t)bi * RST)[l16];
  float4 avv = reinterpret_cast<const float4*>(a_vec)[l16];
  const float* x2b = x12y + (size_t)b * NN * RST + DOUT;           // stride RST
  const float* yb = x12y + (size_t)b * NN * RST + 2 * DOUT + lane; // y col
  const unsigned long long* e64 =
      reinterpret_cast<const unsigned long long*>(ews + (size_t)bi * ESTRIDE);

  float lsum = 0.f, acc = 0.f;
  for (int s0 = 0; s0 < nzt4; s0 += 4) {
    unsigned long long ej = e64[s0 >> 2];   // 4 edge ids, broadcast load
    int j0 = (int)(ej & 0xFFFFu);
    int j1 = (int)((ej >> 16) & 0xFFFFu);
    int j2 = (int)((ej >> 32) & 0xFFFFu);
    int j3 = (int)(ej >> 48);
    // y gathers: 4 x 256B coalesced, independent of the score chain
    float yv0 = yb[(size_t)j0 * RST];
    float yv1 = yb[(size_t)j1 * RST];
    float yv2 = yb[(size_t)j2 * RST];
    float yv3 = yb[(size_t)j3 * RST];
    // this group's edge score
    int jg = (g0 == 0) ? j0 : (g0 == 1) ? j1 : (g0 == 2) ? j2 : j3;
    float4 x2v = *reinterpret_cast<const float4*>(
        x2b + (size_t)jg * RST + l16 * 4);  // 4 groups x 256B
    float z, sc = 0.f;
    z = x1v.x + x2v.x; sc = fmaf(z >= 0.f ? z : SLOPE * z, avv.x, sc);
    z = x1v.y + x2v.y; sc = fmaf(z >= 0.f ? z : SLOPE * z, avv.y, sc);
    z = x1v.z + x2v.z; sc = fmaf(z >= 0.f ? z : SLOPE * z, avv.z, sc);
    z = x1v.w + x2v.w; sc = fmaf(z >= 0.f ? z : SLOPE * z, avv.w, sc);
    sc += __shfl_xor(sc, 8, 16);
    sc += __shfl_xor(sc, 4, 16);
    sc += __shfl_xor(sc, 2, 16);
    sc += __shfl_xor(sc, 1, 16);
    float e = fast_edge_exp(sc);
    if (s0 + g0 >= nzt) e = 0.f;  // mask pad edges
    lsum += e;
    acc = fmaf(__shfl(e, 0, 64), yv0, acc);
    acc = fmaf(__shfl(e, 16, 64), yv1, acc);
    acc = fmaf(__shfl(e, 32, 64), yv2, acc);
    acc = fmaf(__shfl(e, 48, 64), yv3, acc);
  }

#pragma unroll
  for (int off = 32; off > 0; off >>= 1) lsum += __shfl_xor(lsum, off, 64);
  float oo = acc * (16.f / lsum);
  oo = oo >= 0.f ? oo : SLOPE * oo;
  out[(size_t)bi * DOUT + lane] = oo;
}

extern "C" void kernel_launch(void* const* d_in, const int* in_sizes, int n_in,
                              void* d_out, int out_size, void* d_ws, size_t ws_size,
                              hipStream_t stream) {
  const float* x = (const float*)d_in[0];
  const float* A_shape = (const float*)d_in[1];
  const float* w1 = (const float*)d_in[2];
  const float* w2 = (const float*)d_in[3];
  const float* a = (const float*)d_in[4];
  const float* lin_w = (const float*)d_in[5];
  float* out = (float*)d_out;
  char* ws = (char*)d_ws;
  float* x12y = (float*)ws;                                  // 3 MB
  int* cnt = (int*)(ws + (size_t)BB * NN * RST * 4);         // 16 KB
  unsigned short* ews = (unsigned short*)(ws + (size_t)BB * NN * RST * 4 + BB * NN * 4);

  proj_compact_kernel<<<NPROJ + NCOMP, 256, 0, stream>>>(
      x, w1, w2, lin_w, A_shape, x12y, cnt, ews);
  gat_edge_kernel<<<BB * NN, 64, 0, stream>>>(a, x12y, cnt, ews, out);
}

// Round 6
// 97.259 us; speedup vs baseline: 1.1463x; 1.0074x over previous
//
#include <hip/hip_runtime.h>
#include <math.h>

#define BB 4
#define NN 1024
#define DIN 128
#define DOUT 64
#define SLOPE 0.01f
#define RST 192      // x12y row stride (floats): [x1(64) | x2(64) | y(64)]
#define R1 8         // rows per projection block
#define NPROJ (BB * NN / R1)   // 512 projection blocks
#define NCOMP (BB * NN / 4)    // 1024 compaction blocks (4 rows each)
#define ESTRIDE 1056 // u16 elems per edge-list row (8B aligned; max used 1032)

// ws layout:
//   [0)        x12y : BB*NN*RST f32  = 3 MB
//   [3145728)  cnt  : BB*NN i32      = 16 KB
//   [3162112)  ews  : BB*NN*ESTRIDE u16 = 8.6 MB

__device__ __forceinline__ float fast_edge_exp(float sc) {
  // e = exp(8*tanh(sc/8)); tanh via exp, clamped so __expf stays finite
  float z = sc * 0.125f;
  z = fminf(10.f, fmaxf(-10.f, z));
  float u = __expf(2.f * z);
  float th = (u - 1.f) / (u + 1.f);
  return __expf(8.f * th);
}

// Kernel 1: heterogeneous grid.
//  blocks [0,512): 8-row projection GEMM tile (y = x@lw^T folded in, since
//    (A@x)@lw^T == A@(x@lw^T)).
//  blocks [512,1536): mask compaction, one wave per row -> u16 edge lists.
//  Compaction is independent of projection, so the 16 MB mask HBM read
//  overlaps the projection compute instead of serializing in kernel 2.
__global__ __launch_bounds__(256, 2) void proj_compact_kernel(
    const float* __restrict__ x, const float* __restrict__ w1,
    const float* __restrict__ w2, const float* __restrict__ lin_w,
    const float* __restrict__ A_shape, float* __restrict__ x12y,
    int* __restrict__ cnt, unsigned short* __restrict__ ews) {
  int tid = threadIdx.x;

  if (blockIdx.x >= NPROJ) {
    // ---- compaction path: 4 rows/block, one per wave, wave-synchronous ----
    int lane = tid & 63;
    int r = (blockIdx.x - NPROJ) * 4 + (tid >> 6);   // global row bi
    const float* mask_row = A_shape + (size_t)r * NN;
    float mv[16];
#pragma unroll
    for (int c = 0; c < 16; ++c) mv[c] = mask_row[c * 64 + lane];
    unsigned short* er = ews + (size_t)r * ESTRIDE;
    int base = 0;
#pragma unroll
    for (int c = 0; c < 16; ++c) {
      bool pred = (mv[c] != 0.f);
      unsigned long long m = __ballot(pred);
      int prefix = __popcll(m & ((1ull << lane) - 1ull));
      if (pred) er[base + prefix] = (unsigned short)(c * 64 + lane);
      base += __popcll(m);  // wave-uniform
    }
    if (lane < 8) er[base + lane] = (unsigned short)(r & (NN - 1));  // pads
    if (lane == 0) cnt[r] = base;
    return;
  }

  // ---- projection path ----
  int d = tid & 63;
  int g = tid >> 6;
  __shared__ __align__(16) float xl[R1][DIN];      // 4 KB
  __shared__ float lwT[DIN][DOUT + 1];             // 33.3 KB, pad: no bank conflicts
  int row0 = blockIdx.x * R1;

  {  // stage 8 x-rows: 1024 floats = 256 float4, coalesced
    const float4* xs = reinterpret_cast<const float4*>(x + (size_t)row0 * DIN);
    reinterpret_cast<float4*>(&xl[0][0])[tid] = xs[tid];
  }
#pragma unroll
  for (int i = 0; i < 32; ++i) {  // stage lin_w [64][128] -> lwT [128][65]
    int idx = i * 256 + tid;      // coalesced read; write stride 65: conflict-free
    lwT[idx & 127][idx >> 7] = lin_w[idx];
  }
  __syncthreads();

  float a1[2] = {0.f, 0.f};
  float a2[2] = {0.f, 0.f};
  float a3[2] = {0.f, 0.f};
  const float* w1c = w1 + d;
  const float* w2c = w2 + d;
#pragma unroll 4
  for (int k = 0; k < DIN; ++k) {
    float wv1 = w1c[k * DOUT];   // 256B/wave, L1-hot
    float wv2 = w2c[k * DOUT];
    float wv3 = lwT[k][d];       // LDS, conflict-free
#pragma unroll
    for (int r = 0; r < 2; ++r) {
      float xv = xl[g * 2 + r][k];  // LDS broadcast
      a1[r] = fmaf(xv, wv1, a1[r]);
      a2[r] = fmaf(xv, wv2, a2[r]);
      a3[r] = fmaf(xv, wv3, a3[r]);
    }
  }
#pragma unroll
  for (int r = 0; r < 2; ++r) {
    size_t o = (size_t)(row0 + g * 2 + r) * RST;
    x12y[o + d] = a1[r];              // 256B coalesced per wave
    x12y[o + DOUT + d] = a2[r];
    x12y[o + 2 * DOUT + d] = a3[r];
  }
}

// Kernel 2: edge pass, TWO WAVES per (b,i) row (stride-8 interleave over
// 4-edge groups) -> 8192 waves = 8 waves/SIMD for latency hiding. Per wave:
// 4 edges/iter (one per 16-lane group) from a single u64 of u16 ids; score +
// exp + y-aggregation fused; normalization deferred (out = acc*16/sum, 16x
// because all 16 lanes of a group accumulate their e into lsum). One LDS
// combine at the end.
__global__ __launch_bounds__(128, 8) void gat_edge_kernel(
    const float* __restrict__ a_vec, const float* __restrict__ x12y,
    const int* __restrict__ cnt, const unsigned short* __restrict__ ews,
    float* __restrict__ out) {
  int bi = blockIdx.x;  // b*N + i
  int b = bi >> 10;
  int tid = threadIdx.x;
  int lane = tid & 63;
  int w = tid >> 6;
  int l16 = lane & 15;
  int g0 = lane >> 4;

  __shared__ float aggh[2][DOUT];
  __shared__ float wsum[2];

  int nzt = cnt[bi];
  int nzt8 = (nzt + 7) & ~7;
  float4 x1v = reinterpret_cast<const float4*>(x12y + (size_t)bi * RST)[l16];
  float4 avv = reinterpret_cast<const float4*>(a_vec)[l16];
  const float* x2b = x12y + (size_t)b * NN * RST + DOUT;           // stride RST
  const float* yb = x12y + (size_t)b * NN * RST + 2 * DOUT + lane; // y col
  const unsigned long long* e64 =
      reinterpret_cast<const unsigned long long*>(ews + (size_t)bi * ESTRIDE);

  float lsum = 0.f, acc = 0.f;
  for (int s0 = 4 * w; s0 < nzt8; s0 += 8) {
    unsigned long long ej = e64[s0 >> 2];   // 4 edge ids, broadcast load
    int j0 = (int)(ej & 0xFFFFu);
    int j1 = (int)((ej >> 16) & 0xFFFFu);
    int j2 = (int)((ej >> 32) & 0xFFFFu);
    int j3 = (int)(ej >> 48);
    // y gathers: 4 x 256B coalesced, independent of the score chain
    float yv0 = yb[(size_t)j0 * RST];
    float yv1 = yb[(size_t)j1 * RST];
    float yv2 = yb[(size_t)j2 * RST];
    float yv3 = yb[(size_t)j3 * RST];
    // this group's edge score
    int jg = (g0 == 0) ? j0 : (g0 == 1) ? j1 : (g0 == 2) ? j2 : j3;
    float4 x2v = *reinterpret_cast<const float4*>(
        x2b + (size_t)jg * RST + l16 * 4);  // 4 groups x 256B
    float z, sc = 0.f;
    z = x1v.x + x2v.x; sc = fmaf(z >= 0.f ? z : SLOPE * z, avv.x, sc);
    z = x1v.y + x2v.y; sc = fmaf(z >= 0.f ? z : SLOPE * z, avv.y, sc);
    z = x1v.z + x2v.z; sc = fmaf(z >= 0.f ? z : SLOPE * z, avv.z, sc);
    z = x1v.w + x2v.w; sc = fmaf(z >= 0.f ? z : SLOPE * z, avv.w, sc);
    sc += __shfl_xor(sc, 8, 16);
    sc += __shfl_xor(sc, 4, 16);
    sc += __shfl_xor(sc, 2, 16);
    sc += __shfl_xor(sc, 1, 16);
    float e = fast_edge_exp(sc);
    if (s0 + g0 >= nzt) e = 0.f;  // mask pad edges
    lsum += e;
    acc = fmaf(__shfl(e, 0, 64), yv0, acc);
    acc = fmaf(__shfl(e, 16, 64), yv1, acc);
    acc = fmaf(__shfl(e, 32, 64), yv2, acc);
    acc = fmaf(__shfl(e, 48, 64), yv3, acc);
  }

#pragma unroll
  for (int off = 32; off > 0; off >>= 1) lsum += __shfl_xor(lsum, off, 64);
  if (lane == 0) wsum[w] = lsum;
  aggh[w][lane] = acc;
  __syncthreads();

  if (tid < DOUT) {
    float inv = 16.f / (wsum[0] + wsum[1]);
    float oo = (aggh[0][tid] + aggh[1][tid]) * inv;
    oo = oo >= 0.f ? oo : SLOPE * oo;
    out[(size_t)bi * DOUT + tid] = oo;
  }
}

extern "C" void kernel_launch(void* const* d_in, const int* in_sizes, int n_in,
                              void* d_out, int out_size, void* d_ws, size_t ws_size,
                              hipStream_t stream) {
  const float* x = (const float*)d_in[0];
  const float* A_shape = (const float*)d_in[1];
  const float* w1 = (const float*)d_in[2];
  const float* w2 = (const float*)d_in[3];
  const float* a = (const float*)d_in[4];
  const float* lin_w = (const float*)d_in[5];
  float* out = (float*)d_out;
  char* ws = (char*)d_ws;
  float* x12y = (float*)ws;                                  // 3 MB
  int* cnt = (int*)(ws + (size_t)BB * NN * RST * 4);         // 16 KB
  unsigned short* ews = (unsigned short*)(ws + (size_t)BB * NN * RST * 4 + BB * NN * 4);

  proj_compact_kernel<<<NPROJ + NCOMP, 256, 0, stream>>>(
      x, w1, w2, lin_w, A_shape, x12y, cnt, ews);
  gat_edge_kernel<<<BB * NN, 128, 0, stream>>>(a, x12y, cnt, ews, out);
}